// Round 1
// baseline (77.048 us; speedup 1.0000x reference)
//
#include <hip/hip_runtime.h>

// SpanIndexEncoder via difference-array + prefix scan.
// out[t,f] = sum_n [start_n <= t <= end_n] * embed[n,f]
//          = prefix_sum_t( delta[t,f] ),  delta[s]+=v, delta[e+1]-=v  (valid spans only)
//
// Dispatches:
//  0. hipMemsetAsync: zero delta[2048][128] + chunkSum[256][128] in d_ws (1.15 MB)
//  1. scatter: one thread per (node,f); <=4 fp32 atomics (delta AND fused 8-token
//     chunk sums -- first scan level computed for free during the scatter).
//  2. scan: block b (of 256) sums chunkSum[0..b) as the carry, then running-sums
//     its 8 delta rows and stores coalesced 512B rows.
//
// Replaces the old per-tile design's 43.5K redundant embed row-reads
// (~170 covering spans re-read per 8-token tile) with 131K one-touch scatters.

#define T_TOKENS 2048
#define N_NODES  1024
#define F        128
#define CHUNK    8
#define NCHUNK   (T_TOKENS / CHUNK)          // 256

#define DELTA_FLOATS (T_TOKENS * F)          // 262144
#define CSUM_FLOATS  (NCHUNK * F)            // 32768
#define WS_BYTES     ((size_t)(DELTA_FLOATS + CSUM_FLOATS) * 4)  // 1,179,648 B

__global__ __launch_bounds__(256)
void scatter_kernel(const int* __restrict__ starts,
                    const int* __restrict__ ends,
                    const float* __restrict__ embed,
                    float* __restrict__ ws)
{
    const int g = blockIdx.x * 256 + threadIdx.x;   // 0..131071 == n*F + f
    const int f = g & (F - 1);
    const int n = g >> 7;
    // All 64 lanes of a wave share the same n (wave spans half a feature row),
    // so starts/ends are wave-uniform loads -> one L2 line per wave.
    const int s = starts[n];
    const int e = ends[n];
    if (s > e) return;                               // invalid span: no tokens
    const float v = embed[g];                        // fully coalesced

    float* delta = ws;
    float* csum  = ws + DELTA_FLOATS;

    atomicAdd(&delta[s * F + f], v);
    atomicAdd(&csum[(s >> 3) * F + f], v);           // fused scan level-1
    const int e1 = e + 1;
    if (e1 < T_TOKENS) {                             // e1==2048 never affects t<=2047
        atomicAdd(&delta[e1 * F + f], -v);
        atomicAdd(&csum[(e1 >> 3) * F + f], -v);
    }
}

__global__ __launch_bounds__(128)
void scan_kernel(const float* __restrict__ ws, float* __restrict__ out)
{
    const int b = blockIdx.x;        // chunk 0..255
    const int f = threadIdx.x;       // 0..127
    const float* delta = ws;
    const float* csum  = ws + DELTA_FLOATS;

    // Carry = sum of all preceding chunk sums. <=255 coalesced, independent
    // L2 loads feeding 4 accumulator chains -> issue-bound, not latency-bound.
    float c0 = 0.f, c1 = 0.f, c2 = 0.f, c3 = 0.f;
    int bp = 0;
    for (; bp + 4 <= b; bp += 4) {
        c0 += csum[(bp + 0) * F + f];
        c1 += csum[(bp + 1) * F + f];
        c2 += csum[(bp + 2) * F + f];
        c3 += csum[(bp + 3) * F + f];
    }
    for (; bp < b; ++bp) c0 += csum[bp * F + f];
    float run = (c0 + c1) + (c2 + c3);

    // Local running sum over this chunk's 8 delta rows; coalesced 512B stores.
    const int t0 = b * CHUNK;
    #pragma unroll
    for (int r = 0; r < CHUNK; ++r) {
        run += delta[(t0 + r) * F + f];
        out[(t0 + r) * F + f] = run;
    }
}

extern "C" void kernel_launch(void* const* d_in, const int* in_sizes, int n_in,
                              void* d_out, int out_size, void* d_ws, size_t ws_size,
                              hipStream_t stream) {
    const int*   starts = (const int*)d_in[0];
    const int*   ends   = (const int*)d_in[1];
    const float* embed  = (const float*)d_in[2];
    float*       out    = (float*)d_out;
    float*       ws     = (float*)d_ws;

    hipMemsetAsync(d_ws, 0, WS_BYTES, stream);
    scatter_kernel<<<(N_NODES * F) / 256, 256, 0, stream>>>(starts, ends, embed, ws);
    scan_kernel<<<NCHUNK, 128, 0, stream>>>(ws, out);
}